// Round 2
// baseline (277.491 us; speedup 1.0000x reference)
//
#include <hip/hip_runtime.h>
#include <hip/hip_bf16.h>

#define N_ROWS 16384
#define D_COLS 2048
#define NUM_LABELS 1024
#define NUM_CAMS 8
#define NUM_SEG (NUM_LABELS * NUM_CAMS)   // 8192
#define MAXPER 64     // list capacity per segment (true max ~12 for this input)
#define R_REG 16      // rows kept in registers; cnt>R_REG falls back to re-read (never hit here)
#define F4_PER_ROW (D_COLS / 4)           // 512 float4 per row

// ---------------- kernel 1: build per-segment row lists ----------------
__global__ void build_lists_kernel(const int* __restrict__ labels,
                                   const int* __restrict__ cams,
                                   int* __restrict__ counts,
                                   int* __restrict__ lists) {
    int i = blockIdx.x * blockDim.x + threadIdx.x;
    if (i < N_ROWS) {
        int seg = labels[i] * NUM_CAMS + cams[i];
        int pos = atomicAdd(&counts[seg], 1);
        if (pos < MAXPER) lists[seg * MAXPER + pos] = i;
    }
}

__device__ __forceinline__ float smooth_l1(float d) {
    float ad = fabsf(d);
    return ad < 1.0f ? 0.5f * d * d : ad - 0.5f;
}

// ---------------- kernel 2: one block per (segment, column-half) ----------------
// 256 threads; thread owns ONE float4 chunk: off = half*256 + tid.
// Single pass over feats: rows cached in registers, mean computed, loss from regs.
__global__ __launch_bounds__(256) void seg_loss_kernel(const float* __restrict__ feats,
                                                       const int* __restrict__ counts,
                                                       const int* __restrict__ lists,
                                                       float* __restrict__ out) {
    int seg  = blockIdx.x >> 1;
    int half = blockIdx.x & 1;
    int tid  = threadIdx.x;
    int cnt  = counts[seg];
    float local = 0.0f;

    if (cnt > 0) {
        int rows = cnt < MAXPER ? cnt : MAXPER;
        const int* lst = lists + seg * MAXPER;
        int off = half * 256 + tid;                  // float4 index within row
        const float4* base = (const float4*)feats;

        // 1) preload row indices (wave-uniform broadcasts, independent)
        int idx[R_REG];
#pragma unroll
        for (int r = 0; r < R_REG; ++r)
            idx[r] = (r < rows) ? lst[r] : -1;

        // 2) issue all row loads independently (max MLP), keep in registers
        float4 v[R_REG];
#pragma unroll
        for (int r = 0; r < R_REG; ++r) {
            v[r] = make_float4(0.f, 0.f, 0.f, 0.f);
            if (idx[r] >= 0)
                v[r] = base[(size_t)idx[r] * F4_PER_ROW + off];
        }

        // 3) sum (zeros contribute nothing) + rare overflow rows
        float mx = 0.f, my = 0.f, mz = 0.f, mw = 0.f;
#pragma unroll
        for (int r = 0; r < R_REG; ++r) {
            mx += v[r].x; my += v[r].y; mz += v[r].z; mw += v[r].w;
        }
        for (int r = R_REG; r < rows; ++r) {         // cold path, never hit for this input
            float4 a = base[(size_t)lst[r] * F4_PER_ROW + off];
            mx += a.x; my += a.y; mz += a.z; mw += a.w;
        }
        float inv = 1.0f / (float)cnt;
        mx *= inv; my *= inv; mz *= inv; mw *= inv;

        // 4) SmoothL1 against mean, straight from registers
#pragma unroll
        for (int r = 0; r < R_REG; ++r) {
            if (idx[r] >= 0) {
                local += smooth_l1(v[r].x - mx) + smooth_l1(v[r].y - my)
                       + smooth_l1(v[r].z - mz) + smooth_l1(v[r].w - mw);
            }
        }
        for (int r = R_REG; r < rows; ++r) {         // cold path
            float4 a = base[(size_t)lst[r] * F4_PER_ROW + off];
            local += smooth_l1(a.x - mx) + smooth_l1(a.y - my)
                   + smooth_l1(a.z - mz) + smooth_l1(a.w - mw);
        }
    }

    // block reduction: wave64 shuffle then LDS across 4 waves
    for (int o = 32; o > 0; o >>= 1)
        local += __shfl_down(local, o, 64);

    __shared__ float wsum[4];
    int lane = tid & 63;
    int wid  = tid >> 6;
    if (lane == 0) wsum[wid] = local;
    __syncthreads();
    if (tid == 0) {
        float s = wsum[0] + wsum[1] + wsum[2] + wsum[3];
        if (s != 0.0f)
            atomicAdd(out, s * (1.0f / ((float)N_ROWS * (float)D_COLS)));
    }
}

extern "C" void kernel_launch(void* const* d_in, const int* in_sizes, int n_in,
                              void* d_out, int out_size, void* d_ws, size_t ws_size,
                              hipStream_t stream) {
    const float* feats = (const float*)d_in[0];
    const int* labels  = (const int*)d_in[1];
    const int* cams    = (const int*)d_in[2];
    float* out = (float*)d_out;

    // workspace layout: counts[NUM_SEG] | lists[NUM_SEG*MAXPER]
    int* counts = (int*)d_ws;
    int* lists  = counts + NUM_SEG;

    hipMemsetAsync(counts, 0, NUM_SEG * sizeof(int), stream);   // zero counts
    hipMemsetAsync(out, 0, sizeof(float), stream);              // out accumulates atomics

    build_lists_kernel<<<(N_ROWS + 255) / 256, 256, 0, stream>>>(labels, cams, counts, lists);
    seg_loss_kernel<<<NUM_SEG * 2, 256, 0, stream>>>(feats, counts, lists, out);
}

// Round 3
// 213.556 us; speedup vs baseline: 1.2994x; 1.2994x over previous
//
#include <hip/hip_runtime.h>
#include <hip/hip_bf16.h>

#define N_ROWS 16384
#define D_COLS 2048
#define NUM_LABELS 1024
#define NUM_CAMS 8
#define NUM_SEG (NUM_LABELS * NUM_CAMS)   // 8192
#define MAXPER 64                          // list capacity per segment (true max ~12 here)

// ---------------- kernel 1: build per-segment row lists ----------------
__global__ void build_lists_kernel(const int* __restrict__ labels,
                                   const int* __restrict__ cams,
                                   int* __restrict__ counts,
                                   int* __restrict__ lists) {
    int i = blockIdx.x * blockDim.x + threadIdx.x;
    if (i < N_ROWS) {
        int seg = labels[i] * NUM_CAMS + cams[i];
        int pos = atomicAdd(&counts[seg], 1);
        if (pos < MAXPER) lists[seg * MAXPER + pos] = i;
    }
}

__device__ __forceinline__ float smooth_l1(float d) {
    float ad = fabsf(d);
    return ad < 1.0f ? 0.5f * d * d : ad - 0.5f;
}

// ---------------- kernel 2: one block per segment ----------------
// 256 threads; thread t owns float4 chunks t and t+256 (full 8KB row coverage).
// Two passes (mean, then SmoothL1); row list staged in LDS; NO global atomics —
// partial sum stored to partials[blockIdx.x].
__global__ __launch_bounds__(256) void seg_loss_kernel(const float* __restrict__ feats,
                                                       const int* __restrict__ counts,
                                                       const int* __restrict__ lists,
                                                       float* __restrict__ partials) {
    int seg = blockIdx.x;
    int tid = threadIdx.x;
    int cnt = counts[seg];
    float local = 0.0f;

    __shared__ int slist[MAXPER];

    if (cnt > 0) {
        int rows = cnt < MAXPER ? cnt : MAXPER;

        // stage row indices in LDS once (kills the dependent global lst load per pass)
        if (tid < rows) slist[tid] = lists[seg * MAXPER + tid];
        __syncthreads();

        float m0x = 0.f, m0y = 0.f, m0z = 0.f, m0w = 0.f;
        float m1x = 0.f, m1y = 0.f, m1z = 0.f, m1w = 0.f;

        // pass 1: sum over rows
        for (int r = 0; r < rows; ++r) {
            const float4* rp = (const float4*)(feats + (size_t)slist[r] * D_COLS);
            float4 a = rp[tid];
            float4 b = rp[tid + 256];
            m0x += a.x; m0y += a.y; m0z += a.z; m0w += a.w;
            m1x += b.x; m1y += b.y; m1z += b.z; m1w += b.w;
        }
        float inv = 1.0f / (float)cnt;
        m0x *= inv; m0y *= inv; m0z *= inv; m0w *= inv;
        m1x *= inv; m1y *= inv; m1z *= inv; m1w *= inv;

        // pass 2: SmoothL1 vs mean (rows hot in L1/L2)
        for (int r = 0; r < rows; ++r) {
            const float4* rp = (const float4*)(feats + (size_t)slist[r] * D_COLS);
            float4 a = rp[tid];
            float4 b = rp[tid + 256];
            local += smooth_l1(a.x - m0x) + smooth_l1(a.y - m0y)
                   + smooth_l1(a.z - m0z) + smooth_l1(a.w - m0w);
            local += smooth_l1(b.x - m1x) + smooth_l1(b.y - m1y)
                   + smooth_l1(b.z - m1z) + smooth_l1(b.w - m1w);
        }
    }

    // block reduction: wave64 shuffle then LDS across 4 waves
    for (int o = 32; o > 0; o >>= 1)
        local += __shfl_down(local, o, 64);

    __shared__ float wsum[4];
    int lane = tid & 63;
    int wid  = tid >> 6;
    if (lane == 0) wsum[wid] = local;
    __syncthreads();
    if (tid == 0)
        partials[seg] = wsum[0] + wsum[1] + wsum[2] + wsum[3];  // plain store, no atomic
}

// ---------------- kernel 3: reduce 8192 partials -> scalar loss ----------------
__global__ __launch_bounds__(256) void reduce_kernel(const float* __restrict__ partials,
                                                     float* __restrict__ out) {
    int tid = threadIdx.x;
    float s = 0.0f;
    for (int i = tid; i < NUM_SEG; i += 256)
        s += partials[i];

    for (int o = 32; o > 0; o >>= 1)
        s += __shfl_down(s, o, 64);

    __shared__ float wsum[4];
    int lane = tid & 63;
    int wid  = tid >> 6;
    if (lane == 0) wsum[wid] = s;
    __syncthreads();
    if (tid == 0)
        out[0] = (wsum[0] + wsum[1] + wsum[2] + wsum[3])
               * (1.0f / ((float)N_ROWS * (float)D_COLS));
}

extern "C" void kernel_launch(void* const* d_in, const int* in_sizes, int n_in,
                              void* d_out, int out_size, void* d_ws, size_t ws_size,
                              hipStream_t stream) {
    const float* feats = (const float*)d_in[0];
    const int* labels  = (const int*)d_in[1];
    const int* cams    = (const int*)d_in[2];
    float* out = (float*)d_out;

    // workspace layout: counts[NUM_SEG] | lists[NUM_SEG*MAXPER] | partials[NUM_SEG]
    int* counts     = (int*)d_ws;
    int* lists      = counts + NUM_SEG;
    float* partials = (float*)(lists + NUM_SEG * MAXPER);

    hipMemsetAsync(counts, 0, NUM_SEG * sizeof(int), stream);   // only counts need zeroing

    build_lists_kernel<<<(N_ROWS + 255) / 256, 256, 0, stream>>>(labels, cams, counts, lists);
    seg_loss_kernel<<<NUM_SEG, 256, 0, stream>>>(feats, counts, lists, partials);
    reduce_kernel<<<1, 256, 0, stream>>>(partials, out);
}